// Round 7
// baseline (352.875 us; speedup 1.0000x reference)
//
#include <hip/hip_runtime.h>
#include <cstdint>

#define N_EDGES 12288
#define ROWLEN  2432      // 19*128 floats per edge
#define CAP     2048      // per-system bucket capacity (buckets avg 768)

typedef __bf16 bf16;
typedef __bf16 bf16x8 __attribute__((ext_vector_type(8)));
typedef __bf16 bf16x4 __attribute__((ext_vector_type(4)));
typedef float  f32x4  __attribute__((ext_vector_type(4)));

#define ELEMS0 (640*640)
#define ELEMS1 (1024*1024)
#define ELEMS2 (768*768)

// ws byte offsets (no xb buffer: A is cast f32->bf16 inside the GEMM)
#define WS_IDX_OFF   1024
#define WS_BIAS_OFF  (WS_IDX_OFF + 16*CAP*4)                 // 132096
#define WS_W_OFF     (WS_BIAS_OFF + 16*640*4)                // 173056
#define WZ_ELEMS     ((size_t)16*(ELEMS0+ELEMS1+ELEMS2))     // 32.77M bf16

// After the SO(2) "hat" fold every branch is a square GEMM with K == N.
template<int B> struct Cfg;
template<> struct Cfg<0> { static constexpr int K=640,  KS=640, XOFF=0,    NT=5;
                           static constexpr size_t WOFF=0; };
template<> struct Cfg<1> { static constexpr int K=1024, KS=512, XOFF=640,  NT=8;
                           static constexpr size_t WOFF=(size_t)16*ELEMS0; };
template<> struct Cfg<2> { static constexpr int K=768,  KS=384, XOFF=1664, NT=6;
                           static constexpr size_t WOFF=(size_t)16*ELEMS0+(size_t)16*ELEMS1; };

__device__ __forceinline__ void async_copy16(const void* g, void* l) {
  // global -> LDS direct copy, 16B/lane; LDS dest = wave-uniform base + lane*16.
  auto gp = reinterpret_cast<const __attribute__((address_space(1))) unsigned int*>(
      reinterpret_cast<uintptr_t>(g));
  auto lp = reinterpret_cast<__attribute__((address_space(3))) unsigned int*>(
      (unsigned int)reinterpret_cast<uintptr_t>(l));
  __builtin_amdgcn_global_load_lds(gp, lp, 16, 0, 0);
}

// ---------------- weight mixing + hat fold + swizzle + bf16 cast ----------------
// dst layout per (branch, system): [kblk][chunk128][kgrp:4][n:128][k8:8] bf16.
template<int B>
__device__ __forceinline__ void mix_body(const float* __restrict__ Wsrc,
                                         const float* ce_s,
                                         unsigned short* __restrict__ Wz, int pos) {
  constexpr int N = Cfg<B>::K, KS = Cfg<B>::KS, NT = N / 128, HALF = N / 2;
  constexpr int SRC_STRIDE = KS * N;
  constexpr size_t DST_STRIDE = (size_t)Cfg<B>::K * N;
  int nn = pos & 127, kgrp = (pos >> 7) & 3, rest = pos >> 9;
  int nt = rest % NT, kblk = rest / NT;
  int i0 = kblk * 32 + kgrp * 8;
  int c  = nt * 128 + nn;
  int si = i0, sc = c; float sg = 1.f;
  if (B > 0 && i0 >= KS) {                      // lower half of hat: [-W2 | W1]
    si = i0 - KS;
    if (c < HALF) { sc = c + HALF; sg = -1.f; } else { sc = c - HALF; }
  }
  float w[8][8];
  const float* p0 = Wsrc + (size_t)si * N + sc;
#pragma unroll
  for (int e = 0; e < 8; ++e) {
    const float* p = p0 + (size_t)e * SRC_STRIDE;
#pragma unroll
    for (int j = 0; j < 8; ++j)
      w[e][j] = sg * p[(size_t)j * N];
  }
  unsigned short* db = Wz + Cfg<B>::WOFF + (size_t)pos * 8;
#pragma unroll
  for (int s = 0; s < 16; ++s) {
    float a[8] = {0, 0, 0, 0, 0, 0, 0, 0};
#pragma unroll
    for (int e = 0; e < 8; ++e) {
      float cc = ce_s[s * 8 + e];
#pragma unroll
      for (int j = 0; j < 8; ++j) a[j] += cc * w[e][j];
    }
    bf16x8 v;
#pragma unroll
    for (int j = 0; j < 8; ++j) v[j] = (bf16)a[j];
    *(bf16x8*)(db + s * DST_STRIDE) = v;
  }
}

// ---------------- fused prep: mix (1000 blocks) + bucket (48) + bias (40) ----
// The three parts are mutually independent; fusing removes two sequential
// launch gaps and lets bucket/bias co-schedule under mix's occupancy.
__global__ __launch_bounds__(256) void prep_all(
    const float* __restrict__ W0, const float* __restrict__ W1,
    const float* __restrict__ W2, const float* __restrict__ ce,
    unsigned short* __restrict__ Wz,
    const int* __restrict__ eb, int* __restrict__ counts, int* __restrict__ idxb,
    const float* __restrict__ b0, float* __restrict__ bias) {
  __shared__ float ce_s[128];
  __shared__ int hcnt[16], hbase[16];
  int tid = threadIdx.x;
  int bx = blockIdx.x;
  if (bx < 1000) {                               // ---- weight mix ----
    if (tid < 128) ce_s[tid] = ce[tid];
    __syncthreads();
    if (bx < 200)      mix_body<0>(W0, ce_s, Wz, bx * 256 + tid);
    else if (bx < 712) mix_body<1>(W1, ce_s, Wz, (bx - 200) * 256 + tid);
    else               mix_body<2>(W2, ce_s, Wz, (bx - 712) * 256 + tid);
  } else if (bx < 1048) {                        // ---- bucketing ----
    int t = (bx - 1000) * 256 + tid;
    if (tid < 16) hcnt[tid] = 0;
    __syncthreads();
    int s = -1, lp = 0;
    if (t < N_EDGES) { s = eb[t]; lp = atomicAdd(&hcnt[s], 1); }
    __syncthreads();
    if (tid < 16) hbase[tid] = atomicAdd(counts + tid, hcnt[tid]);
    __syncthreads();
    if (s >= 0) { int p = hbase[s] + lp; if (p < CAP) idxb[s * CAP + p] = t; }
  } else {                                       // ---- mixed bias ----
    int t = (bx - 1048) * 256 + tid;             // 0..10239
    int s = t / 640, c = t - s * 640;
    float a = 0.f;
#pragma unroll
    for (int e = 0; e < 8; ++e) a += ce[s * 8 + e] * b0[e * 640 + c];
    bias[t] = a;
  }
}

// ---------------- grouped GEMM: 128x256 tile, 4 waves, depth-2 A+B pipeline --
// A-load latency was the uncovered stall: x is re-fetched from HBM every
// dispatch (FETCH == sizeof(x); out's write-allocate evicts it from LLC), so
// loadA at depth 1 exposed ~300+ cyc per K-step at writeA, broadcast to all
// waves by the barrier. Now TWO named sreg sets (static indexing, rule 20) and
// a manually 2x-unrolled K-loop put loadA(kb+2) ~2 iterations (~1200 cyc)
// ahead of its writeA wait. In-order vmcnt retirement preserves the invariant
// that waiting on loadA(kb+1) also retires stageB(kb+1) (issued just before).
// In-loop we never drain vmcnt(0).
template<int B>
__device__ __forceinline__ void gemm_body(
    const float* __restrict__ x, const char* __restrict__ zeros,
    const unsigned short* __restrict__ Wz,
    const int* __restrict__ counts, const int* __restrict__ idxb,
    const float* __restrict__ bias, float* __restrict__ out,
    int s, int mt, int nt2, char* sm, int* eidx)
{
  constexpr int K = Cfg<B>::K, NT = Cfg<B>::NT, KB = K / 32, XOFF = Cfg<B>::XOFF;
  static_assert((K / 32) % 2 == 0, "KB must be even for the 2x-unrolled loop");
  int cnt = counts[s];
  int m0 = mt * 128;
  if (m0 >= cnt) return;
  int tid = threadIdx.x;
  if (tid < 128) eidx[tid] = (m0 + tid < cnt) ? idxb[s * CAP + m0 + tid] : -1;
  __syncthreads();
  // LDS: A bufs 2x8KB ([kq:4][row:128] 16B slots, row XOR-swizzled), B 3x16KB.
  char* Acur = sm;          char* Anxt = sm + 8192;
  char* Bc = sm + 16384;    char* Bm = sm + 32768;    char* Bn = sm + 49152;
  int wv = tid >> 6, ln = tid & 63;
  int wm = wv >> 1, wn = wv & 1;          // 2m x 2n waves, each owns 64x128 output
  int kq = ln >> 4, lm = ln & 15;
  int c0 = nt2 * 2;
  // A source: 8 threads/row, full-line reads (round-6 layout, conflict-free).
  int c16 = tid & 7, rbase = tid >> 3;    // rbase 0..31
  int kq_w = c16 >> 1, half = c16 & 1;    // dest plane + 8B half of 16B chunk
  const char* arow4[4]; int kinc4[4];
#pragma unroll
  for (int i = 0; i < 4; ++i) {
    int e = eidx[rbase + 32 * i];
    if (e >= 0) { arow4[i] = (const char*)(x + (size_t)e * ROWLEN + XOFF); kinc4[i] = 128; }
    else        { arow4[i] = zeros; kinc4[i] = 0; }
  }
  const unsigned short* wb = Wz + Cfg<B>::WOFF + (size_t)s * K * K;

  auto loadA2 = [&](int kb, f32x4& r0, f32x4& r1, f32x4& r2, f32x4& r3)
      __attribute__((always_inline)) {
    r0 = *(const f32x4*)(arow4[0] + (size_t)kb * kinc4[0] + c16 * 16);
    r1 = *(const f32x4*)(arow4[1] + (size_t)kb * kinc4[1] + c16 * 16);
    r2 = *(const f32x4*)(arow4[2] + (size_t)kb * kinc4[2] + c16 * 16);
    r3 = *(const f32x4*)(arow4[3] + (size_t)kb * kinc4[3] + c16 * 16);
  };
  auto writeA2 = [&](char* dst, f32x4& r0, f32x4& r1, f32x4& r2, f32x4& r3)
      __attribute__((always_inline)) {
    f32x4 rr[4] = {r0, r1, r2, r3};
#pragma unroll
    for (int i = 0; i < 4; ++i) {
      int r = rbase + 32 * i;
      bf16x4 v;
      v[0] = (bf16)rr[i][0]; v[1] = (bf16)rr[i][1];
      v[2] = (bf16)rr[i][2]; v[3] = (bf16)rr[i][3];
      *(bf16x4*)(dst + kq_w * 2048 + ((r ^ (kq_w << 1)) * 16) + half * 8) = v;
    }
  };
  auto stageB = [&](int kb, char* dst) __attribute__((always_inline)) {
    const unsigned short* base = wb + (size_t)kb * (NT * 4096);
#pragma unroll
    for (int i = 0; i < 4; ++i) {
      int c = i * 256 + tid;                       // 1024 16B chunks per buf
      int ck = c0 + (c >> 9); if (ck > NT - 1) ck = NT - 1;   // clamp (dup, discarded)
      async_copy16(base + (size_t)ck * 4096 + (c & 511) * 8,
                   dst + (i * 256 + wv * 64) * 16);
    }
  };

  f32x4 acc[4][8];
#pragma unroll
  for (int i = 0; i < 4; ++i)
#pragma unroll
    for (int j = 0; j < 8; ++j) {
      acc[i][j][0] = 0.f; acc[i][j][1] = 0.f; acc[i][j][2] = 0.f; acc[i][j][3] = 0.f;
    }

  // One K-step; OLD regs feed this step's writeA (loaded 2 iters ago),
  // NEW regs are filled for 2 iters ahead.
  auto kstep = [&](int kb, f32x4& o0, f32x4& o1, f32x4& o2, f32x4& o3,
                           f32x4& n0, f32x4& n1, f32x4& n2, f32x4& n3)
      __attribute__((always_inline)) {
    if (kb + 2 < KB) {
      stageB(kb + 2, Bn);                         // B depth-2 (16 gl_lds)
      loadA2(kb + 2, n0, n1, n2, n3);             // A depth-2 (16 loads)
    }
    __builtin_amdgcn_sched_barrier(0);            // pin: issue loads before MFMA
    bf16x8 af[4], bq[8];
#pragma unroll
    for (int mi = 0; mi < 4; ++mi) {
      int r = wm * 64 + mi * 16 + lm;
      af[mi] = *(const bf16x8*)(Acur + kq * 2048 + ((r ^ (kq << 1)) * 16));
    }
#pragma unroll
    for (int ni = 0; ni < 8; ++ni)
      bq[ni] = *(const bf16x8*)(Bc + wn * 8192 + kq * 2048 + (ni * 16 + lm) * 16);
    __builtin_amdgcn_s_setprio(1);
#pragma unroll
    for (int mi = 0; mi < 4; ++mi)
#pragma unroll
      for (int ni = 0; ni < 8; ++ni)
        acc[mi][ni] = __builtin_amdgcn_mfma_f32_16x16x32_bf16(af[mi], bq[ni], acc[mi][ni], 0, 0, 0);
    __builtin_amdgcn_s_setprio(0);
    if (kb + 1 < KB)
      writeA2(Anxt, o0, o1, o2, o3);   // auto vmcnt retires loadA(kb+1)+B(kb+1)
    asm volatile("s_waitcnt lgkmcnt(0)" ::: "memory");  // own ds_writes visible
    __builtin_amdgcn_s_barrier();                 // raw: vmcnt stays nonzero
    __builtin_amdgcn_sched_barrier(0);
    { char* t = Acur; Acur = Anxt; Anxt = t; }
    { char* tb = Bc; Bc = Bm; Bm = Bn; Bn = tb; }
  };

  f32x4 a0, a1, a2, a3, b0, b1, b2, b3;
  // Prologue: stageB(0) FIRST so writeA's wait on loadA(0) retires it too.
  stageB(0, Bc);
  loadA2(0, a0, a1, a2, a3);
  writeA2(Acur, a0, a1, a2, a3);       // waits loadA(0) -> B(0) also landed
  stageB(1, Bm);
  loadA2(1, a0, a1, a2, a3);           // OLD for iter 0
  asm volatile("s_waitcnt lgkmcnt(0)" ::: "memory");
  __builtin_amdgcn_s_barrier();
  __builtin_amdgcn_sched_barrier(0);

#pragma unroll 1
  for (int kb = 0; kb < KB; kb += 2) {
    kstep(kb,     a0, a1, a2, a3,  b0, b1, b2, b3);
    kstep(kb + 1, b0, b1, b2, b3,  a0, a1, a2, a3);
  }
  // epilogue: C/D layout col=lane&15, row=(lane>>4)*4+reg
  int cc = c0 + wn;
  if (cc >= NT) return;
  float bv[8] = {0, 0, 0, 0, 0, 0, 0, 0};
  if (B == 0) {
#pragma unroll
    for (int ni = 0; ni < 8; ++ni)
      bv[ni] = bias[s * 640 + cc * 128 + ni * 16 + lm];
  }
#pragma unroll
  for (int mi = 0; mi < 4; ++mi) {
#pragma unroll
    for (int r = 0; r < 4; ++r) {
      int row = wm * 64 + mi * 16 + kq * 4 + r;
      int e = eidx[row];
      if (e < 0) continue;
      float* po = out + (size_t)e * ROWLEN + XOFF + cc * 128 + lm;
#pragma unroll
      for (int ni = 0; ni < 8; ++ni) po[ni * 16] = acc[mi][ni][r] + bv[ni];
    }
  }
}

__global__ __launch_bounds__(256, 2) void gemm_all(
    const float* __restrict__ x, const char* __restrict__ zeros,
    const unsigned short* __restrict__ Wz,
    const int* __restrict__ counts, const int* __restrict__ idxb,
    const float* __restrict__ bias, float* __restrict__ out) {
  extern __shared__ char sm[];
  __shared__ int eidx[128];
  // Bijective XCD swizzle: all 160 blocks of system s land on XCD (s&7) ->
  // W panel and A-slabs stay L2/LLC-local across mt re-reads.
  // grid = 2560 = 8 xcd * 320; per XCD: systems (xcd) then (xcd+8), bx fastest.
  int g = blockIdx.x;
  int xcd = g & 7, j = g >> 3;          // j in 0..319
  int s = xcd + 8 * (j / 160);
  int r = j % 160;
  int mt = r / 10, bx = r % 10;         // mt: 16 x 128-row tiles; bx: 3+4+3 col-pairs
  if (bx < 3)      gemm_body<0>(x, zeros, Wz, counts, idxb, bias, out, s, mt, bx,     sm, eidx);
  else if (bx < 7) gemm_body<1>(x, zeros, Wz, counts, idxb, bias, out, s, mt, bx - 3, sm, eidx);
  else             gemm_body<2>(x, zeros, Wz, counts, idxb, bias, out, s, mt, bx - 7, sm, eidx);
}

extern "C" void kernel_launch(void* const* d_in, const int* in_sizes, int n_in,
                              void* d_out, int out_size, void* d_ws, size_t ws_size,
                              hipStream_t stream) {
  const float* x  = (const float*)d_in[0];
  // d_in[1] = x_edge: unused by the reference
  const float* ce = (const float*)d_in[2];
  const int*   eb = (const int*)d_in[3];
  const float* W0 = (const float*)d_in[4];
  const float* b0 = (const float*)d_in[5];
  const float* W1 = (const float*)d_in[6];
  const float* W2 = (const float*)d_in[7];
  float* out = (float*)d_out;
  char* ws = (char*)d_ws;
  int*   counts = (int*)ws;
  char*  zeros  = ws + 256;                      // zeroed by the memset below
  int*   idxb   = (int*)(ws + WS_IDX_OFF);
  float* bias   = (float*)(ws + WS_BIAS_OFF);
  unsigned short* Wz = (unsigned short*)(ws + WS_W_OFF);

  hipMemsetAsync(ws, 0, 1024, stream);           // counts + zeros region
  prep_all<<<1088, 256, 0, stream>>>(W0, W1, W2, ce, Wz, eb, counts, idxb, b0, bias);
  gemm_all<<<2560, 256, 65536, stream>>>(x, zeros, Wz, counts, idxb, bias, out);
}

// Round 8
// 320.230 us; speedup vs baseline: 1.1019x; 1.1019x over previous
//
#include <hip/hip_runtime.h>
#include <cstdint>

#define N_EDGES 12288
#define ROWLEN  2432      // 19*128 floats per edge
#define CAP     2048      // per-system bucket capacity (buckets avg 768)

typedef __bf16 bf16;
typedef __bf16 bf16x8 __attribute__((ext_vector_type(8)));
typedef __bf16 bf16x4 __attribute__((ext_vector_type(4)));
typedef float  f32x4  __attribute__((ext_vector_type(4)));

#define ELEMS0 (640*640)
#define ELEMS1 (1024*1024)
#define ELEMS2 (768*768)

// ws byte offsets (no xb buffer: A is cast f32->bf16 inside the GEMM)
#define WS_IDX_OFF   1024
#define WS_BIAS_OFF  (WS_IDX_OFF + 16*CAP*4)                 // 132096
#define WS_W_OFF     (WS_BIAS_OFF + 16*640*4)                // 173056
#define WZ_ELEMS     ((size_t)16*(ELEMS0+ELEMS1+ELEMS2))     // 32.77M bf16

// After the SO(2) "hat" fold every branch is a square GEMM with K == N.
template<int B> struct Cfg;
template<> struct Cfg<0> { static constexpr int K=640,  KS=640, XOFF=0,    NT=5;
                           static constexpr size_t WOFF=0; };
template<> struct Cfg<1> { static constexpr int K=1024, KS=512, XOFF=640,  NT=8;
                           static constexpr size_t WOFF=(size_t)16*ELEMS0; };
template<> struct Cfg<2> { static constexpr int K=768,  KS=384, XOFF=1664, NT=6;
                           static constexpr size_t WOFF=(size_t)16*ELEMS0+(size_t)16*ELEMS1; };

__device__ __forceinline__ void async_copy16(const void* g, void* l) {
  // global -> LDS direct copy, 16B/lane; LDS dest = wave-uniform base + lane*16.
  auto gp = reinterpret_cast<const __attribute__((address_space(1))) unsigned int*>(
      reinterpret_cast<uintptr_t>(g));
  auto lp = reinterpret_cast<__attribute__((address_space(3))) unsigned int*>(
      (unsigned int)reinterpret_cast<uintptr_t>(l));
  __builtin_amdgcn_global_load_lds(gp, lp, 16, 0, 0);
}

// ---------------- weight mixing + hat fold + swizzle + bf16 cast ----------------
// dst layout per (branch, system): [kblk][chunk128][kgrp:4][n:128][k8:8] bf16.
template<int B>
__device__ __forceinline__ void mix_body(const float* __restrict__ Wsrc,
                                         const float* ce_s,
                                         unsigned short* __restrict__ Wz, int pos) {
  constexpr int N = Cfg<B>::K, KS = Cfg<B>::KS, NT = N / 128, HALF = N / 2;
  constexpr int SRC_STRIDE = KS * N;
  constexpr size_t DST_STRIDE = (size_t)Cfg<B>::K * N;
  int nn = pos & 127, kgrp = (pos >> 7) & 3, rest = pos >> 9;
  int nt = rest % NT, kblk = rest / NT;
  int i0 = kblk * 32 + kgrp * 8;
  int c  = nt * 128 + nn;
  int si = i0, sc = c; float sg = 1.f;
  if (B > 0 && i0 >= KS) {                      // lower half of hat: [-W2 | W1]
    si = i0 - KS;
    if (c < HALF) { sc = c + HALF; sg = -1.f; } else { sc = c - HALF; }
  }
  float w[8][8];
  const float* p0 = Wsrc + (size_t)si * N + sc;
#pragma unroll
  for (int e = 0; e < 8; ++e) {
    const float* p = p0 + (size_t)e * SRC_STRIDE;
#pragma unroll
    for (int j = 0; j < 8; ++j)
      w[e][j] = sg * p[(size_t)j * N];
  }
  unsigned short* db = Wz + Cfg<B>::WOFF + (size_t)pos * 8;
#pragma unroll
  for (int s = 0; s < 16; ++s) {
    float a[8] = {0, 0, 0, 0, 0, 0, 0, 0};
#pragma unroll
    for (int e = 0; e < 8; ++e) {
      float cc = ce_s[s * 8 + e];
#pragma unroll
      for (int j = 0; j < 8; ++j) a[j] += cc * w[e][j];
    }
    bf16x8 v;
#pragma unroll
    for (int j = 0; j < 8; ++j) v[j] = (bf16)a[j];
    *(bf16x8*)(db + s * DST_STRIDE) = v;
  }
}

// ---------------- fused prep: mix (1000 blocks) + bucket (48) + bias (40) ----
__global__ __launch_bounds__(256) void prep_all(
    const float* __restrict__ W0, const float* __restrict__ W1,
    const float* __restrict__ W2, const float* __restrict__ ce,
    unsigned short* __restrict__ Wz,
    const int* __restrict__ eb, int* __restrict__ counts, int* __restrict__ idxb,
    const float* __restrict__ b0, float* __restrict__ bias) {
  __shared__ float ce_s[128];
  __shared__ int hcnt[16], hbase[16];
  int tid = threadIdx.x;
  int bx = blockIdx.x;
  if (bx < 1000) {                               // ---- weight mix ----
    if (tid < 128) ce_s[tid] = ce[tid];
    __syncthreads();
    if (bx < 200)      mix_body<0>(W0, ce_s, Wz, bx * 256 + tid);
    else if (bx < 712) mix_body<1>(W1, ce_s, Wz, (bx - 200) * 256 + tid);
    else               mix_body<2>(W2, ce_s, Wz, (bx - 712) * 256 + tid);
  } else if (bx < 1048) {                        // ---- bucketing ----
    int t = (bx - 1000) * 256 + tid;
    if (tid < 16) hcnt[tid] = 0;
    __syncthreads();
    int s = -1, lp = 0;
    if (t < N_EDGES) { s = eb[t]; lp = atomicAdd(&hcnt[s], 1); }
    __syncthreads();
    if (tid < 16) hbase[tid] = atomicAdd(counts + tid, hcnt[tid]);
    __syncthreads();
    if (s >= 0) { int p = hbase[s] + lp; if (p < CAP) idxb[s * CAP + p] = t; }
  } else {                                       // ---- mixed bias ----
    int t = (bx - 1048) * 256 + tid;             // 0..10239
    int s = t / 640, c = t - s * 640;
    float a = 0.f;
#pragma unroll
    for (int e = 0; e < 8; ++e) a += ce[s * 8 + e] * b0[e * 640 + c];
    bias[t] = a;
  }
}

// ---------------- grouped GEMM: 128x256 tile, 8 waves, counted-vmcnt pipeline -
// Occupancy was the limit: all prior variants ran 8 waves/CU (acc[4][8]=128
// AGPR + ~120 VGPR ~= 250 regs/wave -> 2 waves/SIMD hard cap) with Occ ~17%,
// MfmaUtil ~17%, zero bank conflicts -> latency-bound. Now 8 waves/block as
// 2m x 4n, each wave owns 64x64: acc[4][4]=64, af[4]+bq[4]=32, sreg 8,
// 32-bit A offsets off the x SGPR base -> ~125 regs total, fits
// __launch_bounds__(512,4) = 128 regs/wave -> 2 blocks x 8 waves = 16
// waves/CU (2x occupancy). LDS layouts, XOR swizzle, counted-vmcnt invariant
// (writeA's wait on loadA(kb+1) retires stageB(kb+1); never vmcnt(0) in-loop),
// grid, and epilogue mapping unchanged from the 126.5us round-6 kernel.
// Pad rows read x offset 0 (garbage, discarded at e<0 in epilogue) - no zeros
// buffer, saves pointer regs.
template<int B>
__device__ __forceinline__ void gemm_body(
    const float* __restrict__ x,
    const unsigned short* __restrict__ Wz,
    const int* __restrict__ counts, const int* __restrict__ idxb,
    const float* __restrict__ bias, float* __restrict__ out,
    int s, int mt, int nt2, char* sm, int* eidx)
{
  constexpr int K = Cfg<B>::K, NT = Cfg<B>::NT, KB = K / 32, XOFF = Cfg<B>::XOFF;
  int cnt = counts[s];
  int m0 = mt * 128;
  if (m0 >= cnt) return;
  int tid = threadIdx.x;
  if (tid < 128) eidx[tid] = (m0 + tid < cnt) ? idxb[s * CAP + m0 + tid] : -1;
  __syncthreads();
  // LDS: A bufs 2x8KB ([kq:4][row:128] 16B slots, row XOR-swizzled), B 3x16KB.
  char* Acur = sm;          char* Anxt = sm + 8192;
  char* Bc = sm + 16384;    char* Bm = sm + 32768;    char* Bn = sm + 49152;
  int wv = tid >> 6, ln = tid & 63;
  int wm = wv >> 2, wn = wv & 3;          // 2m x 4n waves, each owns 64x64 output
  int kq = ln >> 4, lm = ln & 15;
  int c0 = nt2 * 2;
  // A source: 8 threads/row, full-line reads; thread covers rows rbase + 64*i.
  int c16 = tid & 7, rbase = tid >> 3;    // rbase 0..63
  int kq_w = c16 >> 1, half = c16 & 1;    // dest plane + 8B half of 16B chunk
  const char* xb = (const char*)x;
  unsigned int aoff[2], kinc[2];
#pragma unroll
  for (int i = 0; i < 2; ++i) {
    int e = eidx[rbase + 64 * i];
    aoff[i] = (e >= 0) ? (unsigned int)(((size_t)e * ROWLEN + XOFF) * 4) : 0u;
    kinc[i] = (e >= 0) ? 128u : 0u;
  }
  const unsigned short* wb = Wz + Cfg<B>::WOFF + (size_t)s * K * K;

  f32x4 sreg[2];                                   // staged A (2 rows x 4 f32)
  auto loadA = [&](int kb) __attribute__((always_inline)) {
#pragma unroll
    for (int i = 0; i < 2; ++i)
      sreg[i] = *(const f32x4*)(xb + aoff[i] + kb * kinc[i] + c16 * 16);
  };
  auto writeA = [&](char* dst) __attribute__((always_inline)) {
#pragma unroll
    for (int i = 0; i < 2; ++i) {
      int r = rbase + 64 * i;
      bf16x4 v;
      v[0] = (bf16)sreg[i][0]; v[1] = (bf16)sreg[i][1];
      v[2] = (bf16)sreg[i][2]; v[3] = (bf16)sreg[i][3];
      *(bf16x4*)(dst + kq_w * 2048 + ((r ^ (kq_w << 1)) * 16) + half * 8) = v;
    }
  };
  auto stageB = [&](int kb, char* dst) __attribute__((always_inline)) {
    const unsigned short* base = wb + (size_t)kb * (NT * 4096);
#pragma unroll
    for (int i = 0; i < 2; ++i) {
      int c = i * 512 + tid;                       // 1024 16B chunks per buf
      int ck = c0 + (c >> 9); if (ck > NT - 1) ck = NT - 1;   // clamp (dup, discarded)
      async_copy16(base + (size_t)ck * 4096 + (c & 511) * 8,
                   dst + (i * 512 + wv * 64) * 16);
    }
  };

  f32x4 acc[4][4];
#pragma unroll
  for (int i = 0; i < 4; ++i)
#pragma unroll
    for (int j = 0; j < 4; ++j) {
      acc[i][j][0] = 0.f; acc[i][j][1] = 0.f; acc[i][j][2] = 0.f; acc[i][j][3] = 0.f;
    }

  // Prologue: Acur = A(0) written, Bc = B(0) landed, Bm = B(1) + sreg = A(1)
  // in flight. In-loop we never drain vmcnt(0).
  stageB(0, Bc);
  loadA(0);
  writeA(Acur);                // waits loadA(0) -> stageB(0) also retired
  stageB(1, Bm);
  loadA(1);
  asm volatile("s_waitcnt lgkmcnt(0)" ::: "memory");
  __builtin_amdgcn_s_barrier();
  __builtin_amdgcn_sched_barrier(0);

#pragma unroll 1
  for (int kb = 0; kb < KB; ++kb) {
    if (kb + 2 < KB) stageB(kb + 2, Bn);          // B depth-2 prefetch
    __builtin_amdgcn_sched_barrier(0);            // pin: issue loads before reads
    bf16x8 af[4], bq[4];
#pragma unroll
    for (int mi = 0; mi < 4; ++mi) {
      int r = wm * 64 + mi * 16 + lm;
      af[mi] = *(const bf16x8*)(Acur + kq * 2048 + ((r ^ (kq << 1)) * 16));
    }
#pragma unroll
    for (int ni = 0; ni < 4; ++ni)
      bq[ni] = *(const bf16x8*)(Bc + (wn >> 1) * 8192 + kq * 2048 +
                                (((wn & 1) * 64 + ni * 16 + lm) * 16));
    __builtin_amdgcn_s_setprio(1);
#pragma unroll
    for (int mi = 0; mi < 4; ++mi)
#pragma unroll
      for (int ni = 0; ni < 4; ++ni)
        acc[mi][ni] = __builtin_amdgcn_mfma_f32_16x16x32_bf16(af[mi], bq[ni], acc[mi][ni], 0, 0, 0);
    __builtin_amdgcn_s_setprio(0);
    if (kb + 1 < KB) {
      writeA(Anxt);            // auto vmcnt wait retires loadA(kb+1) AND B(kb+1)
      if (kb + 2 < KB) loadA(kb + 2);             // refill sreg for next writeA
    }
    asm volatile("s_waitcnt lgkmcnt(0)" ::: "memory");  // own ds_writes visible
    __builtin_amdgcn_s_barrier();                 // raw: vmcnt stays nonzero
    __builtin_amdgcn_sched_barrier(0);
    { char* t = Acur; Acur = Anxt; Anxt = t; }
    { char* tb = Bc; Bc = Bm; Bm = Bn; Bn = tb; }
  }
  // epilogue: C/D layout col=lane&15, row=(lane>>4)*4+reg
  int cc = c0 + (wn >> 1);
  if (cc >= NT) return;
  int colb = cc * 128 + (wn & 1) * 64;
  float bv[4] = {0, 0, 0, 0};
  if (B == 0) {
#pragma unroll
    for (int ni = 0; ni < 4; ++ni)
      bv[ni] = bias[s * 640 + colb + ni * 16 + lm];
  }
#pragma unroll
  for (int mi = 0; mi < 4; ++mi) {
#pragma unroll
    for (int r = 0; r < 4; ++r) {
      int row = wm * 64 + mi * 16 + kq * 4 + r;
      int e = eidx[row];
      if (e < 0) continue;
      float* po = out + (size_t)e * ROWLEN + XOFF + colb + lm;
#pragma unroll
      for (int ni = 0; ni < 4; ++ni) po[ni * 16] = acc[mi][ni][r] + bv[ni];
    }
  }
}

__global__ __launch_bounds__(512, 4) void gemm_all(
    const float* __restrict__ x,
    const unsigned short* __restrict__ Wz,
    const int* __restrict__ counts, const int* __restrict__ idxb,
    const float* __restrict__ bias, float* __restrict__ out) {
  extern __shared__ char sm[];
  __shared__ int eidx[128];
  // Bijective XCD swizzle: all 160 blocks of system s land on XCD (s&7) ->
  // W panel and A-slabs stay L2/LLC-local across mt re-reads.
  // grid = 2560 = 8 xcd * 320; per XCD: systems (xcd) then (xcd+8), bx fastest.
  int g = blockIdx.x;
  int xcd = g & 7, j = g >> 3;          // j in 0..319
  int s = xcd + 8 * (j / 160);
  int r = j % 160;
  int mt = r / 10, bx = r % 10;         // mt: 16 x 128-row tiles; bx: 3+4+3 col-pairs
  if (bx < 3)      gemm_body<0>(x, Wz, counts, idxb, bias, out, s, mt, bx,     sm, eidx);
  else if (bx < 7) gemm_body<1>(x, Wz, counts, idxb, bias, out, s, mt, bx - 3, sm, eidx);
  else             gemm_body<2>(x, Wz, counts, idxb, bias, out, s, mt, bx - 7, sm, eidx);
}

extern "C" void kernel_launch(void* const* d_in, const int* in_sizes, int n_in,
                              void* d_out, int out_size, void* d_ws, size_t ws_size,
                              hipStream_t stream) {
  const float* x  = (const float*)d_in[0];
  // d_in[1] = x_edge: unused by the reference
  const float* ce = (const float*)d_in[2];
  const int*   eb = (const int*)d_in[3];
  const float* W0 = (const float*)d_in[4];
  const float* b0 = (const float*)d_in[5];
  const float* W1 = (const float*)d_in[6];
  const float* W2 = (const float*)d_in[7];
  float* out = (float*)d_out;
  char* ws = (char*)d_ws;
  int*   counts = (int*)ws;
  int*   idxb   = (int*)(ws + WS_IDX_OFF);
  float* bias   = (float*)(ws + WS_BIAS_OFF);
  unsigned short* Wz = (unsigned short*)(ws + WS_W_OFF);

  hipMemsetAsync(ws, 0, 1024, stream);           // counts region
  prep_all<<<1088, 256, 0, stream>>>(W0, W1, W2, ce, Wz, eb, counts, idxb, b0, bias);
  gemm_all<<<2560, 512, 65536, stream>>>(x, Wz, counts, idxb, bias, out);
}